// Round 7
// baseline (208.365 us; speedup 1.0000x reference)
//
#include <hip/hip_runtime.h>
#include <math.h>

#define NTOK 32768
#define KCB  1024
#define DIM  64
#define THETA 1.0f

typedef __attribute__((ext_vector_type(8))) short short8;
typedef __attribute__((ext_vector_type(4))) float f32x4;
#define MFMA __builtin_amdgcn_mfma_f32_16x16x32_bf16

// ---- workspace layout (float word offsets) ----
#define WS_XR      0                       // [NTOK*64] rotated vectors f32
#define WS_ENORM   2097152                 // [1024] ||e_k||^2
#define WS_EH      2098176                 // [1024*64 bf16 = 32768 words] E hi
#define WS_EL      2130944                 // [32768 words] E lo
#define WS_COUNTS  2163712                 // [1024]
#define WS_CS      2164736                 // [1024]
#define WS_XRSUM   2165760                 // [64]
#define WS_ESUM    2165824                 // [64]
#define WS_SCAL    2165888                 // [16]: 0=sq_sum 1=xrnorm 2=c*emb^2
#define WS_FLAGCNT 2165904                 // [16] (int, slot 0)
#define WS_IDX     2165920                 // [NTOK] int
#define WS_FLAG    2198688                 // [NTOK] int flagged tokens
#define WS_SORT    2231456                 // [NTOK] int
#define WS_OFF     2264224                 // [1024] int
#define WS_CUR     2265248                 // [1024] int

// ---- output layout (float offsets) ----
#define O_Q    0
#define O_CB   2097152
#define O_CM   2097153
#define O_DV   2097154
#define O_PP   2097155
#define O_IDX  2097156
#define O_CS   2129924
#define O_EW   2130948
#define O_EMB  2196484

__device__ __forceinline__ void hilo(float v, unsigned &h, unsigned &l)
{
    unsigned b  = __float_as_uint(v);
    unsigned hb = (b + 0x7FFFu + ((b >> 16) & 1u)) & 0xFFFF0000u;
    float lof   = v - __uint_as_float(hb);
    unsigned lb = __float_as_uint(lof);
    l = (lb + 0x7FFFu + ((lb >> 16) & 1u)) >> 16;
    h = hb >> 16;
}

// ---------------------------------------------------------------------------
// 1) rotate via cross-lane FWHT; blocks >= 512: enorm + E hi/lo bf16 prep.
__global__ __launch_bounds__(256) void k_rotate_enorm(const float* __restrict__ x,
    const float* __restrict__ E, float* __restrict__ xr, float* __restrict__ enorm,
    unsigned short* __restrict__ eh, unsigned short* __restrict__ el,
    float* __restrict__ xr_sum, float* __restrict__ scal)
{
    int tid = threadIdx.x;
    if (blockIdx.x >= 512) {   // E-prep blocks (4 x 256 codes)
        int k = ((int)blockIdx.x - 512) * 256 + tid;
        const float* ep = E + ((size_t)k << 6);
        unsigned* ehw = (unsigned*)eh + (k << 5);
        unsigned* elw = (unsigned*)el + (k << 5);
        float s = 0.f;
        #pragma unroll
        for (int q = 0; q < 32; ++q) {
            float v0 = ep[2*q], v1 = ep[2*q+1];
            s = fmaf(v0, v0, s); s = fmaf(v1, v1, s);
            unsigned h0, l0, h1, l1;
            hilo(v0, h0, l0);
            hilo(v1, h1, l1);
            ehw[q] = h0 | (h1 << 16);
            elw[q] = l0 | (l1 << 16);
        }
        enorm[k] = s;
        return;
    }
    __shared__ float xs[4][64];
    __shared__ float wred[4];
    int lane = tid & 63, w = tid >> 6;
    int g = blockIdx.x * 4 + w;
    float dsum = 0.f, nrm = 0.f;
    #pragma unroll
    for (int i = 0; i < 4; ++i) {
        int t0 = g * 16 + i * 4;
        const float* src = x + ((size_t)(t0 >> 10) << 16) + lane * 1024 + (t0 & 1023);
        float4 v = *(const float4*)src;
        #pragma unroll
        for (int s = 1; s <= 32; s <<= 1) {
            float sgn = (lane & s) ? -1.f : 1.f;
            float ox = __shfl_xor(v.x, s);
            float oy = __shfl_xor(v.y, s);
            float oz = __shfl_xor(v.z, s);
            float ow = __shfl_xor(v.w, s);
            v.x = fmaf(sgn, v.x, ox);
            v.y = fmaf(sgn, v.y, oy);
            v.z = fmaf(sgn, v.z, oz);
            v.w = fmaf(sgn, v.w, ow);
        }
        float* dst = xr + ((size_t)t0 << 6) + lane;
        dst[0]   = v.x;
        dst[64]  = v.y;
        dst[128] = v.z;
        dst[192] = v.w;
        dsum += v.x + v.y + v.z + v.w;
        nrm  += v.x*v.x + v.y*v.y + v.z*v.z + v.w*v.w;
    }
    xs[w][lane] = dsum;
    #pragma unroll
    for (int m = 32; m >= 1; m >>= 1) nrm += __shfl_xor(nrm, m);
    if (lane == 0) wred[w] = nrm;
    __syncthreads();
    if (tid < 64) atomicAdd(&xr_sum[tid], xs[0][tid] + xs[1][tid] + xs[2][tid] + xs[3][tid]);
    if (tid == 0) atomicAdd(&scal[1], wred[0] + wred[1] + wred[2] + wred[3]);
}

// ---------------------------------------------------------------------------
// 2) MFMA argmin. Block = 64 tokens (4 waves x 16) x all 1024 codes (4 chunks
//    of 256 staged in LDS, XOR-swizzled 16B units). Per wave: A = token rows
//    as bf16 hi/lo frags in regs (converted once); per 16-code step: 4 LDS
//    B-frag reads + 6 MFMAs (hh+hl+lh per K-half) + fold to (b1,b2,idx).
//    Tokens with b2-b1 < THETA flagged for exact f32 fixup.
__global__ __launch_bounds__(256) void k_argmin(const float* __restrict__ xr,
    const unsigned short* __restrict__ eh, const unsigned short* __restrict__ el,
    const float* __restrict__ enorm, int* __restrict__ idxw,
    float* __restrict__ out_idx, float* __restrict__ counts,
    int* __restrict__ flagcnt, int* __restrict__ flaglist)
{
    __shared__ uint4 ehs[2048];    // 256 codes x 128B (swizzled)
    __shared__ uint4 els[2048];
    __shared__ float ens[256];
    int tid = threadIdx.x;
    int lane = tid & 63, w = tid >> 6;
    int tx = lane & 15, gq = lane >> 4;
    int t0w = ((int)blockIdx.x << 6) + (w << 4);

    // --- A fragments: xr rows -> bf16 hi/lo in registers ---
    short8 ah0, al0, ah1, al1;
    {
        const float* xp = xr + ((size_t)(t0w + tx) << 6) + (gq << 3);
        float4 xa = *(const float4*)(xp);
        float4 xb = *(const float4*)(xp + 4);
        float4 xc = *(const float4*)(xp + 32);
        float4 xd = *(const float4*)(xp + 36);
        float a0v[8] = {xa.x,xa.y,xa.z,xa.w,xb.x,xb.y,xb.z,xb.w};
        float a1v[8] = {xc.x,xc.y,xc.z,xc.w,xd.x,xd.y,xd.z,xd.w};
        #pragma unroll
        for (int j = 0; j < 8; ++j) {
            unsigned h, l;
            hilo(a0v[j], h, l);
            ah0[j] = (short)h; al0[j] = (short)l;
            hilo(a1v[j], h, l);
            ah1[j] = (short)h; al1[j] = (short)l;
        }
    }

    float b1[4], b2[4]; int idx[4];
    #pragma unroll
    for (int r = 0; r < 4; ++r) { b1[r] = 3.4e38f; b2[r] = 3.4e38f; idx[r] = 0; }

    int swz0 = gq ^ (tx & 7);          // swizzled unit idx, constant per lane
    int swz1 = (4 + gq) ^ (tx & 7);
    const f32x4 z4 = {0.f, 0.f, 0.f, 0.f};

    for (int ch = 0; ch < 4; ++ch) {
        int c0 = ch << 8;
        __syncthreads();
        {   // stage 256 codes of eh/el (+enorm), XOR-swizzled 16B units
            const uint4* ghs = (const uint4*)eh + ((size_t)c0 << 3);
            const uint4* gls = (const uint4*)el + ((size_t)c0 << 3);
            #pragma unroll
            for (int i = 0; i < 8; ++i) {
                int u = (i << 8) + tid;
                int rr = u >> 3, bb = u & 7;
                int bs = bb ^ (rr & 7);
                ehs[(rr << 3) + bs] = ghs[u];
                els[(rr << 3) + bs] = gls[u];
            }
            ens[tid] = enorm[c0 + tid];
        }
        __syncthreads();

        #pragma unroll
        for (int s = 0; s < 16; ++s) {
            int rbase = (s << 4) + tx;                 // local code row
            short8 bh0 = ((const short8*)ehs)[(rbase << 3) + swz0];
            short8 bh1 = ((const short8*)ehs)[(rbase << 3) + swz1];
            short8 bl0 = ((const short8*)els)[(rbase << 3) + swz0];
            short8 bl1 = ((const short8*)els)[(rbase << 3) + swz1];

            f32x4 a0 = MFMA(ah0, bh0, z4, 0, 0, 0);
            a0 = MFMA(ah0, bl0, a0, 0, 0, 0);
            a0 = MFMA(al0, bh0, a0, 0, 0, 0);
            f32x4 a1 = MFMA(ah1, bh1, z4, 0, 0, 0);
            a1 = MFMA(ah1, bl1, a1, 0, 0, 0);
            a1 = MFMA(al1, bh1, a1, 0, 0, 0);

            float en = ens[rbase];
            int kk = c0 + rbase;
            #pragma unroll
            for (int r = 0; r < 4; ++r) {
                float sv = fmaf(-2.f, a0[r], fmaf(-2.f, a1[r], en));
                float mx = fmaxf(sv, b1[r]);           // loser of (sv, old b1)
                b2[r] = fminf(b2[r], mx);
                bool t = sv < b1[r];
                idx[r] = t ? kk : idx[r];
                b1[r] = fminf(b1[r], sv);
            }
        }
    }

    // cross-lane top-2 merge over the 16 code-columns (xor bits 0-3)
    #pragma unroll
    for (int r = 0; r < 4; ++r) {
        float v1 = b1[r], v2 = b2[r]; int id = idx[r];
        #pragma unroll
        for (int m = 1; m <= 8; m <<= 1) {
            float o1 = __shfl_xor(v1, m);
            float o2 = __shfl_xor(v2, m);
            int   oi = __shfl_xor(id, m);
            float nb2 = fminf(fminf(v2, o2), fmaxf(v1, o1));
            bool t = (o1 < v1) || (o1 == v1 && oi < id);
            v1 = t ? o1 : v1;
            id = t ? oi : id;
            v2 = nb2;
        }
        if (tx == 0) {
            int tok = t0w + (gq << 2) + r;     // C row = gq*4 + r
            idxw[tok] = id;
            out_idx[tok] = (float)id;
            atomicAdd(&counts[id], 1.f);
            if (v2 - v1 < THETA) {
                int p = atomicAdd(flagcnt, 1);
                flaglist[p] = tok;
            }
        }
    }
}

// ---------------------------------------------------------------------------
// 3) exact f32 re-scan for flagged (near-tie) tokens; corrects idx/counts.
#define NFWAVE 512
__global__ __launch_bounds__(256) void k_fixup(const float* __restrict__ xr,
    const float* __restrict__ E, const float* __restrict__ enorm,
    const int* __restrict__ flagcnt, const int* __restrict__ flaglist,
    int* __restrict__ idxw, float* __restrict__ out_idx, float* __restrict__ counts)
{
    int lane = threadIdx.x & 63;
    int wid = ((int)blockIdx.x * 256 + threadIdx.x) >> 6;
    int cnt = flagcnt[0];
    for (int i = wid; i < cnt; i += NFWAVE) {
        int tok = flaglist[i];
        const float4* xp = (const float4*)(xr + ((size_t)tok << 6));
        float4 xa[16];
        #pragma unroll
        for (int q = 0; q < 16; ++q) xa[q] = xp[q];
        float best = 3.4e38f; int bidx = 0;
        for (int c = 0; c < 16; ++c) {
            int k = (c << 6) + lane;
            const float4* epp = (const float4*)(E + ((size_t)k << 6));
            float d = 0.f;
            #pragma unroll
            for (int q = 0; q < 16; ++q) {
                float4 e = epp[q];
                d = fmaf(xa[q].x, e.x, d);
                d = fmaf(xa[q].y, e.y, d);
                d = fmaf(xa[q].z, e.z, d);
                d = fmaf(xa[q].w, e.w, d);
            }
            float sv = fmaf(-2.f, d, enorm[k]);
            if (sv < best) { best = sv; bidx = k; }
        }
        #pragma unroll
        for (int m = 1; m <= 32; m <<= 1) {
            float ov = __shfl_xor(best, m);
            int   oi = __shfl_xor(bidx, m);
            if (ov < best || (ov == best && oi < bidx)) { best = ov; bidx = oi; }
        }
        if (lane == 0) {
            int old = idxw[tok];
            if (old != bidx) {
                atomicAdd(&counts[old], -1.f);
                atomicAdd(&counts[bidx], 1.f);
                idxw[tok] = bidx;
                out_idx[tok] = (float)bidx;
            }
        }
    }
}

// ---------------------------------------------------------------------------
// 4) quant output (float4 streaming) + squared-error sum
__global__ __launch_bounds__(256) void k_quant(const float* __restrict__ x,
    const float* __restrict__ E, const int* __restrict__ idxw,
    float* __restrict__ outq, float* __restrict__ scal)
{
    int q = blockIdx.x * 256 + threadIdx.x;
    int n = q >> 4, d4 = q & 15;
    int k = idxw[n];
    float4 xv = ((const float4*)x)[q];
    float4 ev = ((const float4*)E)[(k << 4) + d4];
    float dx = ev.x - xv.x, dy = ev.y - xv.y, dz = ev.z - xv.z, dw_ = ev.w - xv.w;
    ((float4*)outq)[q] = make_float4(xv.x + dx, xv.y + dy, xv.z + dz, xv.w + dw_);
    float sq = dx*dx + dy*dy + dz*dz + dw_*dw_;
    #pragma unroll
    for (int m = 32; m >= 1; m >>= 1) sq += __shfl_xor(sq, m);
    __shared__ float wr[4];
    if ((threadIdx.x & 63) == 0) wr[threadIdx.x >> 6] = sq;
    __syncthreads();
    if (threadIdx.x == 0) atomicAdd(&scal[0], wr[0] + wr[1] + wr[2] + wr[3]);
}

// ---------------------------------------------------------------------------
// 5) EMA cluster size + smoothing + exclusive scan (wave-shuffle)
__global__ __launch_bounds__(1024) void k_ema_scan(const float* __restrict__ ecs,
    const float* __restrict__ counts, float* __restrict__ out_cs,
    float* __restrict__ csw, int* __restrict__ off, int* __restrict__ cur)
{
    __shared__ float wsum[16];
    __shared__ int   wcnt[16];
    __shared__ int   woff[16];
    __shared__ float nss;
    int k = threadIdx.x;
    int lane = k & 63, w = k >> 6;
    float c = counts[k];
    float cs = ecs[k] * 0.99f + 0.01f * c;
    int ci = (int)c;
    int sc = ci;
    #pragma unroll
    for (int o = 1; o < 64; o <<= 1) {
        int t = __shfl_up(sc, o);
        if (lane >= o) sc += t;
    }
    float v = cs;
    #pragma unroll
    for (int m = 32; m >= 1; m >>= 1) v += __shfl_xor(v, m);
    if (lane == 63) wcnt[w] = sc;
    if (lane == 0)  wsum[w] = v;
    __syncthreads();
    if (k < 16) {
        int t = wcnt[k];
        int e = t;
        #pragma unroll
        for (int o = 1; o < 16; o <<= 1) {
            int u = __shfl_up(e, o);
            if (k >= o) e += u;
        }
        woff[k] = e - t;
        if (k == 15) {
            float s = 0.f;
            for (int i = 0; i < 16; ++i) s += wsum[i];
            nss = s;
        }
    }
    __syncthreads();
    int offk = woff[w] + sc - ci;
    off[k] = offk;
    cur[k] = offk;
    float nn = nss;
    float csf = (cs + 1e-5f) / (nn + 1024.f * 1e-5f) * nn;
    out_cs[k] = csf;
    csw[k] = csf;
}

// ---------------------------------------------------------------------------
// 6) counting-sort scatter
__global__ __launch_bounds__(256) void k_scatter(const int* __restrict__ idxw,
    int* __restrict__ cur, int* __restrict__ sorted)
{
    int n = blockIdx.x * 256 + threadIdx.x;
    int k = idxw[n];
    int pos = atomicAdd(&cur[k], 1);
    sorted[pos] = n;
}

// ---------------------------------------------------------------------------
// 7) per-code segmented reduction -> new_ema_w, new_embedding, diversity
__global__ __launch_bounds__(256) void k_dwemb(const float* __restrict__ xr,
    const int* __restrict__ sorted, const int* __restrict__ off,
    const float* __restrict__ counts, const float* __restrict__ csw,
    const float* __restrict__ emaw, float* __restrict__ out_ew,
    float* __restrict__ out_emb, float* __restrict__ e_sum,
    float* __restrict__ scal)
{
    __shared__ float part[3][64];
    int k = blockIdx.x;
    int tid = threadIdx.x;
    int w = tid >> 6, d = tid & 63;
    int a = off[k];
    int cnt = (int)counts[k];
    int end = a + cnt;

    float sum = 0.f;
    for (int t = a + w; t < end; t += 4) {
        int tok = sorted[t];
        sum += xr[((size_t)tok << 6) + d];
    }
    if (w) part[w - 1][d] = sum;
    __syncthreads();
    if (w == 0) {
        float dw = sum + part[0][d] + part[1][d] + part[2][d];
        int i = (k << 6) + d;
        float nw = emaw[i] * 0.99f + 0.01f * dw;
        out_ew[i] = nw;
        float emb = nw / csw[k];
        out_emb[i] = emb;
        if (cnt > 0) {
            float c = (float)cnt;
            atomicAdd(&e_sum[d], c * emb);
            float t2 = c * emb * emb;
            #pragma unroll
            for (int m = 32; m >= 1; m >>= 1) t2 += __shfl_xor(t2, m);
            if (d == 0) atomicAdd(&scal[2], t2);
        }
    }
}

// ---------------------------------------------------------------------------
// 8) finalize scalars
__global__ __launch_bounds__(1024) void k_final(const float* __restrict__ counts,
    const float* __restrict__ scal, const float* __restrict__ xr_sum,
    const float* __restrict__ e_sum, float* __restrict__ out)
{
    int tid = threadIdx.x;
    float a = counts[tid] * (1.f / 32768.f);
    float t = a * logf(a + 1e-10f);
    float dc = (tid < 64) ? e_sum[tid] * xr_sum[tid] : 0.f;
    #pragma unroll
    for (int m = 32; m >= 1; m >>= 1) { t += __shfl_xor(t, m); dc += __shfl_xor(dc, m); }
    __shared__ float wt[16], wd[16];
    if ((tid & 63) == 0) { wt[tid >> 6] = t; wd[tid >> 6] = dc; }
    __syncthreads();
    if (tid == 0) {
        float S = 0.f, Dt = 0.f;
        for (int i = 0; i < 16; ++i) { S += wt[i]; Dt += wd[i]; }
        float cb = scal[0] * (1.f / 2097152.f);
        out[O_CB] = cb;
        out[O_CM] = 0.25f * cb;
        float inv = 1.f / 32768.f;
        out[O_DV] = scal[2] * inv + scal[1] * inv - 2.f * (Dt * inv * inv);
        out[O_PP] = expf(-S);
    }
}

// ---------------------------------------------------------------------------
extern "C" void kernel_launch(void* const* d_in, const int* in_sizes, int n_in,
                              void* d_out, int out_size, void* d_ws, size_t ws_size,
                              hipStream_t stream)
{
    const float* x    = (const float*)d_in[0];
    const float* E    = (const float*)d_in[1];
    const float* emaw = (const float*)d_in[3];
    const float* ecs  = (const float*)d_in[4];
    float* out = (float*)d_out;
    float* ws  = (float*)d_ws;

    // zero: counts, cs, xrsum, esum, scal, flagcnt (contiguous)
    hipMemsetAsync((void*)(ws + WS_COUNTS), 0,
                   (size_t)(WS_IDX - WS_COUNTS) * sizeof(float), stream);

    hipLaunchKernelGGL(k_rotate_enorm, dim3(516), dim3(256), 0, stream,
                       x, E, ws + WS_XR, ws + WS_ENORM,
                       (unsigned short*)(ws + WS_EH), (unsigned short*)(ws + WS_EL),
                       ws + WS_XRSUM, ws + WS_SCAL);
    hipLaunchKernelGGL(k_argmin, dim3(512), dim3(256), 0, stream,
                       ws + WS_XR, (const unsigned short*)(ws + WS_EH),
                       (const unsigned short*)(ws + WS_EL), ws + WS_ENORM,
                       (int*)(ws + WS_IDX), out + O_IDX, ws + WS_COUNTS,
                       (int*)(ws + WS_FLAGCNT), (int*)(ws + WS_FLAG));
    hipLaunchKernelGGL(k_fixup, dim3(128), dim3(256), 0, stream,
                       ws + WS_XR, E, ws + WS_ENORM,
                       (const int*)(ws + WS_FLAGCNT), (const int*)(ws + WS_FLAG),
                       (int*)(ws + WS_IDX), out + O_IDX, ws + WS_COUNTS);
    hipLaunchKernelGGL(k_quant, dim3(2048), dim3(256), 0, stream,
                       x, E, (const int*)(ws + WS_IDX), out + O_Q, ws + WS_SCAL);
    hipLaunchKernelGGL(k_ema_scan, dim3(1), dim3(1024), 0, stream,
                       ecs, ws + WS_COUNTS, out + O_CS, ws + WS_CS,
                       (int*)(ws + WS_OFF), (int*)(ws + WS_CUR));
    hipLaunchKernelGGL(k_scatter, dim3(128), dim3(256), 0, stream,
                       (const int*)(ws + WS_IDX), (int*)(ws + WS_CUR),
                       (int*)(ws + WS_SORT));
    hipLaunchKernelGGL(k_dwemb, dim3(1024), dim3(256), 0, stream,
                       ws + WS_XR, (const int*)(ws + WS_SORT),
                       (const int*)(ws + WS_OFF), ws + WS_COUNTS, ws + WS_CS,
                       emaw, out + O_EW, out + O_EMB, ws + WS_ESUM, ws + WS_SCAL);
    hipLaunchKernelGGL(k_final, dim3(1), dim3(1024), 0, stream,
                       ws + WS_COUNTS, ws + WS_SCAL, ws + WS_XRSUM,
                       ws + WS_ESUM, out);
}

// Round 8
// 177.923 us; speedup vs baseline: 1.1711x; 1.1711x over previous
//
#include <hip/hip_runtime.h>
#include <math.h>

#define NTOK 32768
#define KCB  1024
#define DIM  64
#define THETA 0.02f   // hi/lo-bf16 MFMA dist error bound ~1e-3; 20x margin

typedef __attribute__((ext_vector_type(8))) short short8;
typedef __attribute__((ext_vector_type(4))) float f32x4;
#define MFMA __builtin_amdgcn_mfma_f32_16x16x32_bf16

// ---- workspace layout (float word offsets) ----
#define WS_XR      0                       // [NTOK*64] rotated vectors f32
#define WS_ENORM   2097152                 // [1024] ||e_k||^2
#define WS_EH      2098176                 // [1024*64 bf16 = 32768 words] E hi
#define WS_EL      2130944                 // [32768 words] E lo
#define WS_COUNTS  2163712                 // [1024]
#define WS_CS      2164736                 // [1024]
#define WS_XRSUM   2165760                 // [64]
#define WS_ESUM    2165824                 // [64]
#define WS_SCAL    2165888                 // [16]: 0=sq_sum 1=xrnorm 2=c*emb^2
#define WS_FLAGCNT 2165904                 // [16] (int, slot 0)
#define WS_IDX     2165920                 // [NTOK] int
#define WS_FLAG    2198688                 // [NTOK] int flagged tokens
#define WS_SORT    2231456                 // [NTOK] int
#define WS_OFF     2264224                 // [1024] int
#define WS_CUR     2265248                 // [1024] int

// ---- output layout (float offsets) ----
#define O_Q    0
#define O_CB   2097152
#define O_CM   2097153
#define O_DV   2097154
#define O_PP   2097155
#define O_IDX  2097156
#define O_CS   2129924
#define O_EW   2130948
#define O_EMB  2196484

__device__ __forceinline__ void hilo(float v, unsigned &h, unsigned &l)
{
    unsigned b  = __float_as_uint(v);
    unsigned hb = (b + 0x7FFFu + ((b >> 16) & 1u)) & 0xFFFF0000u;
    float lof   = v - __uint_as_float(hb);
    unsigned lb = __float_as_uint(lof);
    l = (lb + 0x7FFFu + ((lb >> 16) & 1u)) >> 16;
    h = hb >> 16;
}

// ---------------------------------------------------------------------------
// 1) rotate via cross-lane FWHT; blocks >= 512: enorm + E hi/lo bf16 prep.
__global__ __launch_bounds__(256) void k_rotate_enorm(const float* __restrict__ x,
    const float* __restrict__ E, float* __restrict__ xr, float* __restrict__ enorm,
    unsigned short* __restrict__ eh, unsigned short* __restrict__ el,
    float* __restrict__ xr_sum, float* __restrict__ scal)
{
    int tid = threadIdx.x;
    if (blockIdx.x >= 512) {   // E-prep blocks (4 x 256 codes)
        int k = ((int)blockIdx.x - 512) * 256 + tid;
        const float* ep = E + ((size_t)k << 6);
        unsigned* ehw = (unsigned*)eh + (k << 5);
        unsigned* elw = (unsigned*)el + (k << 5);
        float s = 0.f;
        #pragma unroll
        for (int q = 0; q < 32; ++q) {
            float v0 = ep[2*q], v1 = ep[2*q+1];
            s = fmaf(v0, v0, s); s = fmaf(v1, v1, s);
            unsigned h0, l0, h1, l1;
            hilo(v0, h0, l0);
            hilo(v1, h1, l1);
            ehw[q] = h0 | (h1 << 16);
            elw[q] = l0 | (l1 << 16);
        }
        enorm[k] = s;
        return;
    }
    __shared__ float xs[4][64];
    __shared__ float wred[4];
    int lane = tid & 63, w = tid >> 6;
    int g = blockIdx.x * 4 + w;
    float dsum = 0.f, nrm = 0.f;
    #pragma unroll
    for (int i = 0; i < 4; ++i) {
        int t0 = g * 16 + i * 4;
        const float* src = x + ((size_t)(t0 >> 10) << 16) + lane * 1024 + (t0 & 1023);
        float4 v = *(const float4*)src;
        #pragma unroll
        for (int s = 1; s <= 32; s <<= 1) {
            float sgn = (lane & s) ? -1.f : 1.f;
            float ox = __shfl_xor(v.x, s);
            float oy = __shfl_xor(v.y, s);
            float oz = __shfl_xor(v.z, s);
            float ow = __shfl_xor(v.w, s);
            v.x = fmaf(sgn, v.x, ox);
            v.y = fmaf(sgn, v.y, oy);
            v.z = fmaf(sgn, v.z, oz);
            v.w = fmaf(sgn, v.w, ow);
        }
        float* dst = xr + ((size_t)t0 << 6) + lane;
        dst[0]   = v.x;
        dst[64]  = v.y;
        dst[128] = v.z;
        dst[192] = v.w;
        dsum += v.x + v.y + v.z + v.w;
        nrm  += v.x*v.x + v.y*v.y + v.z*v.z + v.w*v.w;
    }
    xs[w][lane] = dsum;
    #pragma unroll
    for (int m = 32; m >= 1; m >>= 1) nrm += __shfl_xor(nrm, m);
    if (lane == 0) wred[w] = nrm;
    __syncthreads();
    if (tid < 64) atomicAdd(&xr_sum[tid], xs[0][tid] + xs[1][tid] + xs[2][tid] + xs[3][tid]);
    if (tid == 0) atomicAdd(&scal[1], wred[0] + wred[1] + wred[2] + wred[3]);
}

// ---------------------------------------------------------------------------
// 2) MFMA argmin. Block = 64 tokens (4 waves x 16) x all 1024 codes (4 chunks
//    of 256 staged in LDS, XOR-swizzled 16B units). Per wave: A = token rows
//    as bf16 hi/lo frags in regs (converted once); per 16-code step: 4 LDS
//    B-frag reads + 6 MFMAs (hh+hl+lh per K-half) + fold to (b1,b2,idx).
//    Tokens with b2-b1 < THETA flagged for exact f32 fixup.
__global__ __launch_bounds__(256) void k_argmin(const float* __restrict__ xr,
    const unsigned short* __restrict__ eh, const unsigned short* __restrict__ el,
    const float* __restrict__ enorm, int* __restrict__ idxw,
    float* __restrict__ out_idx, float* __restrict__ counts,
    int* __restrict__ flagcnt, int* __restrict__ flaglist)
{
    __shared__ uint4 ehs[2048];    // 256 codes x 128B (swizzled)
    __shared__ uint4 els[2048];
    __shared__ float ens[256];
    int tid = threadIdx.x;
    int lane = tid & 63, w = tid >> 6;
    int tx = lane & 15, gq = lane >> 4;
    int t0w = ((int)blockIdx.x << 6) + (w << 4);

    // --- A fragments: xr rows -> bf16 hi/lo in registers ---
    short8 ah0, al0, ah1, al1;
    {
        const float* xp = xr + ((size_t)(t0w + tx) << 6) + (gq << 3);
        float4 xa = *(const float4*)(xp);
        float4 xb = *(const float4*)(xp + 4);
        float4 xc = *(const float4*)(xp + 32);
        float4 xd = *(const float4*)(xp + 36);
        float a0v[8] = {xa.x,xa.y,xa.z,xa.w,xb.x,xb.y,xb.z,xb.w};
        float a1v[8] = {xc.x,xc.y,xc.z,xc.w,xd.x,xd.y,xd.z,xd.w};
        #pragma unroll
        for (int j = 0; j < 8; ++j) {
            unsigned h, l;
            hilo(a0v[j], h, l);
            ah0[j] = (short)h; al0[j] = (short)l;
            hilo(a1v[j], h, l);
            ah1[j] = (short)h; al1[j] = (short)l;
        }
    }

    float b1[4], b2[4]; int idx[4];
    #pragma unroll
    for (int r = 0; r < 4; ++r) { b1[r] = 3.4e38f; b2[r] = 3.4e38f; idx[r] = 0; }

    int swz0 = gq ^ (tx & 7);          // swizzled unit idx, constant per lane
    int swz1 = (4 + gq) ^ (tx & 7);
    const f32x4 z4 = {0.f, 0.f, 0.f, 0.f};

    for (int ch = 0; ch < 4; ++ch) {
        int c0 = ch << 8;
        __syncthreads();
        {   // stage 256 codes of eh/el (+enorm), XOR-swizzled 16B units
            const uint4* ghs = (const uint4*)eh + ((size_t)c0 << 3);
            const uint4* gls = (const uint4*)el + ((size_t)c0 << 3);
            #pragma unroll
            for (int i = 0; i < 8; ++i) {
                int u = (i << 8) + tid;
                int rr = u >> 3, bb = u & 7;
                int bs = bb ^ (rr & 7);
                ehs[(rr << 3) + bs] = ghs[u];
                els[(rr << 3) + bs] = gls[u];
            }
            ens[tid] = enorm[c0 + tid];
        }
        __syncthreads();

        #pragma unroll
        for (int s = 0; s < 16; ++s) {
            int rbase = (s << 4) + tx;                 // local code row
            short8 bh0 = ((const short8*)ehs)[(rbase << 3) + swz0];
            short8 bh1 = ((const short8*)ehs)[(rbase << 3) + swz1];
            short8 bl0 = ((const short8*)els)[(rbase << 3) + swz0];
            short8 bl1 = ((const short8*)els)[(rbase << 3) + swz1];

            f32x4 a0 = MFMA(ah0, bh0, z4, 0, 0, 0);
            a0 = MFMA(ah0, bl0, a0, 0, 0, 0);
            a0 = MFMA(al0, bh0, a0, 0, 0, 0);
            f32x4 a1 = MFMA(ah1, bh1, z4, 0, 0, 0);
            a1 = MFMA(ah1, bl1, a1, 0, 0, 0);
            a1 = MFMA(al1, bh1, a1, 0, 0, 0);

            float en = ens[rbase];
            int kk = c0 + rbase;
            #pragma unroll
            for (int r = 0; r < 4; ++r) {
                float sv = fmaf(-2.f, a0[r], fmaf(-2.f, a1[r], en));
                float mx = fmaxf(sv, b1[r]);           // loser of (sv, old b1)
                b2[r] = fminf(b2[r], mx);
                bool t = sv < b1[r];
                idx[r] = t ? kk : idx[r];
                b1[r] = fminf(b1[r], sv);
            }
        }
    }

    // cross-lane top-2 merge over the 16 code-columns (xor bits 0-3)
    #pragma unroll
    for (int r = 0; r < 4; ++r) {
        float v1 = b1[r], v2 = b2[r]; int id = idx[r];
        #pragma unroll
        for (int m = 1; m <= 8; m <<= 1) {
            float o1 = __shfl_xor(v1, m);
            float o2 = __shfl_xor(v2, m);
            int   oi = __shfl_xor(id, m);
            float nb2 = fminf(fminf(v2, o2), fmaxf(v1, o1));
            bool t = (o1 < v1) || (o1 == v1 && oi < id);
            v1 = t ? o1 : v1;
            id = t ? oi : id;
            v2 = nb2;
        }
        if (tx == 0) {
            int tok = t0w + (gq << 2) + r;     // C row = gq*4 + r
            idxw[tok] = id;
            out_idx[tok] = (float)id;
            atomicAdd(&counts[id], 1.f);
            if (v2 - v1 < THETA) {
                int p = atomicAdd(flagcnt, 1);
                flaglist[p] = tok;
            }
        }
    }
}

// ---------------------------------------------------------------------------
// 3) exact f32 re-scan for flagged (near-tie) tokens; corrects idx/counts.
#define NFWAVE 512
__global__ __launch_bounds__(256) void k_fixup(const float* __restrict__ xr,
    const float* __restrict__ E, const float* __restrict__ enorm,
    const int* __restrict__ flagcnt, const int* __restrict__ flaglist,
    int* __restrict__ idxw, float* __restrict__ out_idx, float* __restrict__ counts)
{
    int lane = threadIdx.x & 63;
    int wid = ((int)blockIdx.x * 256 + threadIdx.x) >> 6;
    int cnt = flagcnt[0];
    for (int i = wid; i < cnt; i += NFWAVE) {
        int tok = flaglist[i];
        const float4* xp = (const float4*)(xr + ((size_t)tok << 6));
        float4 xa[16];
        #pragma unroll
        for (int q = 0; q < 16; ++q) xa[q] = xp[q];
        float best = 3.4e38f; int bidx = 0;
        for (int c = 0; c < 16; ++c) {
            int k = (c << 6) + lane;
            const float4* epp = (const float4*)(E + ((size_t)k << 6));
            float d = 0.f;
            #pragma unroll
            for (int q = 0; q < 16; ++q) {
                float4 e = epp[q];
                d = fmaf(xa[q].x, e.x, d);
                d = fmaf(xa[q].y, e.y, d);
                d = fmaf(xa[q].z, e.z, d);
                d = fmaf(xa[q].w, e.w, d);
            }
            float sv = fmaf(-2.f, d, enorm[k]);
            if (sv < best) { best = sv; bidx = k; }
        }
        #pragma unroll
        for (int m = 1; m <= 32; m <<= 1) {
            float ov = __shfl_xor(best, m);
            int   oi = __shfl_xor(bidx, m);
            if (ov < best || (ov == best && oi < bidx)) { best = ov; bidx = oi; }
        }
        if (lane == 0) {
            int old = idxw[tok];
            if (old != bidx) {
                atomicAdd(&counts[old], -1.f);
                atomicAdd(&counts[bidx], 1.f);
                idxw[tok] = bidx;
                out_idx[tok] = (float)bidx;
            }
        }
    }
}

// ---------------------------------------------------------------------------
// 4) quant output (float4 streaming) + squared-error sum
__global__ __launch_bounds__(256) void k_quant(const float* __restrict__ x,
    const float* __restrict__ E, const int* __restrict__ idxw,
    float* __restrict__ outq, float* __restrict__ scal)
{
    int q = blockIdx.x * 256 + threadIdx.x;
    int n = q >> 4, d4 = q & 15;
    int k = idxw[n];
    float4 xv = ((const float4*)x)[q];
    float4 ev = ((const float4*)E)[(k << 4) + d4];
    float dx = ev.x - xv.x, dy = ev.y - xv.y, dz = ev.z - xv.z, dw_ = ev.w - xv.w;
    ((float4*)outq)[q] = make_float4(xv.x + dx, xv.y + dy, xv.z + dz, xv.w + dw_);
    float sq = dx*dx + dy*dy + dz*dz + dw_*dw_;
    #pragma unroll
    for (int m = 32; m >= 1; m >>= 1) sq += __shfl_xor(sq, m);
    __shared__ float wr[4];
    if ((threadIdx.x & 63) == 0) wr[threadIdx.x >> 6] = sq;
    __syncthreads();
    if (threadIdx.x == 0) atomicAdd(&scal[0], wr[0] + wr[1] + wr[2] + wr[3]);
}

// ---------------------------------------------------------------------------
// 5) EMA cluster size + smoothing + exclusive scan (wave-shuffle)
__global__ __launch_bounds__(1024) void k_ema_scan(const float* __restrict__ ecs,
    const float* __restrict__ counts, float* __restrict__ out_cs,
    float* __restrict__ csw, int* __restrict__ off, int* __restrict__ cur)
{
    __shared__ float wsum[16];
    __shared__ int   wcnt[16];
    __shared__ int   woff[16];
    __shared__ float nss;
    int k = threadIdx.x;
    int lane = k & 63, w = k >> 6;
    float c = counts[k];
    float cs = ecs[k] * 0.99f + 0.01f * c;
    int ci = (int)c;
    int sc = ci;
    #pragma unroll
    for (int o = 1; o < 64; o <<= 1) {
        int t = __shfl_up(sc, o);
        if (lane >= o) sc += t;
    }
    float v = cs;
    #pragma unroll
    for (int m = 32; m >= 1; m >>= 1) v += __shfl_xor(v, m);
    if (lane == 63) wcnt[w] = sc;
    if (lane == 0)  wsum[w] = v;
    __syncthreads();
    if (k < 16) {
        int t = wcnt[k];
        int e = t;
        #pragma unroll
        for (int o = 1; o < 16; o <<= 1) {
            int u = __shfl_up(e, o);
            if (k >= o) e += u;
        }
        woff[k] = e - t;
        if (k == 15) {
            float s = 0.f;
            for (int i = 0; i < 16; ++i) s += wsum[i];
            nss = s;
        }
    }
    __syncthreads();
    int offk = woff[w] + sc - ci;
    off[k] = offk;
    cur[k] = offk;
    float nn = nss;
    float csf = (cs + 1e-5f) / (nn + 1024.f * 1e-5f) * nn;
    out_cs[k] = csf;
    csw[k] = csf;
}

// ---------------------------------------------------------------------------
// 6) counting-sort scatter
__global__ __launch_bounds__(256) void k_scatter(const int* __restrict__ idxw,
    int* __restrict__ cur, int* __restrict__ sorted)
{
    int n = blockIdx.x * 256 + threadIdx.x;
    int k = idxw[n];
    int pos = atomicAdd(&cur[k], 1);
    sorted[pos] = n;
}

// ---------------------------------------------------------------------------
// 7) per-code segmented reduction -> new_ema_w, new_embedding, diversity
__global__ __launch_bounds__(256) void k_dwemb(const float* __restrict__ xr,
    const int* __restrict__ sorted, const int* __restrict__ off,
    const float* __restrict__ counts, const float* __restrict__ csw,
    const float* __restrict__ emaw, float* __restrict__ out_ew,
    float* __restrict__ out_emb, float* __restrict__ e_sum,
    float* __restrict__ scal)
{
    __shared__ float part[3][64];
    int k = blockIdx.x;
    int tid = threadIdx.x;
    int w = tid >> 6, d = tid & 63;
    int a = off[k];
    int cnt = (int)counts[k];
    int end = a + cnt;

    float sum = 0.f;
    for (int t = a + w; t < end; t += 4) {
        int tok = sorted[t];
        sum += xr[((size_t)tok << 6) + d];
    }
    if (w) part[w - 1][d] = sum;
    __syncthreads();
    if (w == 0) {
        float dw = sum + part[0][d] + part[1][d] + part[2][d];
        int i = (k << 6) + d;
        float nw = emaw[i] * 0.99f + 0.01f * dw;
        out_ew[i] = nw;
        float emb = nw / csw[k];
        out_emb[i] = emb;
        if (cnt > 0) {
            float c = (float)cnt;
            atomicAdd(&e_sum[d], c * emb);
            float t2 = c * emb * emb;
            #pragma unroll
            for (int m = 32; m >= 1; m >>= 1) t2 += __shfl_xor(t2, m);
            if (d == 0) atomicAdd(&scal[2], t2);
        }
    }
}

// ---------------------------------------------------------------------------
// 8) finalize scalars
__global__ __launch_bounds__(1024) void k_final(const float* __restrict__ counts,
    const float* __restrict__ scal, const float* __restrict__ xr_sum,
    const float* __restrict__ e_sum, float* __restrict__ out)
{
    int tid = threadIdx.x;
    float a = counts[tid] * (1.f / 32768.f);
    float t = a * logf(a + 1e-10f);
    float dc = (tid < 64) ? e_sum[tid] * xr_sum[tid] : 0.f;
    #pragma unroll
    for (int m = 32; m >= 1; m >>= 1) { t += __shfl_xor(t, m); dc += __shfl_xor(dc, m); }
    __shared__ float wt[16], wd[16];
    if ((tid & 63) == 0) { wt[tid >> 6] = t; wd[tid >> 6] = dc; }
    __syncthreads();
    if (tid == 0) {
        float S = 0.f, Dt = 0.f;
        for (int i = 0; i < 16; ++i) { S += wt[i]; Dt += wd[i]; }
        float cb = scal[0] * (1.f / 2097152.f);
        out[O_CB] = cb;
        out[O_CM] = 0.25f * cb;
        float inv = 1.f / 32768.f;
        out[O_DV] = scal[2] * inv + scal[1] * inv - 2.f * (Dt * inv * inv);
        out[O_PP] = expf(-S);
    }
}

// ---------------------------------------------------------------------------
extern "C" void kernel_launch(void* const* d_in, const int* in_sizes, int n_in,
                              void* d_out, int out_size, void* d_ws, size_t ws_size,
                              hipStream_t stream)
{
    const float* x    = (const float*)d_in[0];
    const float* E    = (const float*)d_in[1];
    const float* emaw = (const float*)d_in[3];
    const float* ecs  = (const float*)d_in[4];
    float* out = (float*)d_out;
    float* ws  = (float*)d_ws;

    // zero: counts, cs, xrsum, esum, scal, flagcnt (contiguous)
    hipMemsetAsync((void*)(ws + WS_COUNTS), 0,
                   (size_t)(WS_IDX - WS_COUNTS) * sizeof(float), stream);

    hipLaunchKernelGGL(k_rotate_enorm, dim3(516), dim3(256), 0, stream,
                       x, E, ws + WS_XR, ws + WS_ENORM,
                       (unsigned short*)(ws + WS_EH), (unsigned short*)(ws + WS_EL),
                       ws + WS_XRSUM, ws + WS_SCAL);
    hipLaunchKernelGGL(k_argmin, dim3(512), dim3(256), 0, stream,
                       ws + WS_XR, (const unsigned short*)(ws + WS_EH),
                       (const unsigned short*)(ws + WS_EL), ws + WS_ENORM,
                       (int*)(ws + WS_IDX), out + O_IDX, ws + WS_COUNTS,
                       (int*)(ws + WS_FLAGCNT), (int*)(ws + WS_FLAG));
    hipLaunchKernelGGL(k_fixup, dim3(128), dim3(256), 0, stream,
                       ws + WS_XR, E, ws + WS_ENORM,
                       (const int*)(ws + WS_FLAGCNT), (const int*)(ws + WS_FLAG),
                       (int*)(ws + WS_IDX), out + O_IDX, ws + WS_COUNTS);
    hipLaunchKernelGGL(k_quant, dim3(2048), dim3(256), 0, stream,
                       x, E, (const int*)(ws + WS_IDX), out + O_Q, ws + WS_SCAL);
    hipLaunchKernelGGL(k_ema_scan, dim3(1), dim3(1024), 0, stream,
                       ecs, ws + WS_COUNTS, out + O_CS, ws + WS_CS,
                       (int*)(ws + WS_OFF), (int*)(ws + WS_CUR));
    hipLaunchKernelGGL(k_scatter, dim3(128), dim3(256), 0, stream,
                       (const int*)(ws + WS_IDX), (int*)(ws + WS_CUR),
                       (int*)(ws + WS_SORT));
    hipLaunchKernelGGL(k_dwemb, dim3(1024), dim3(256), 0, stream,
                       ws + WS_XR, (const int*)(ws + WS_SORT),
                       (const int*)(ws + WS_OFF), ws + WS_COUNTS, ws + WS_CS,
                       emaw, out + O_EW, out + O_EMB, ws + WS_ESUM, ws + WS_SCAL);
    hipLaunchKernelGGL(k_final, dim3(1), dim3(1024), 0, stream,
                       ws + WS_COUNTS, ws + WS_SCAL, ws + WS_XRSUM,
                       ws + WS_ESUM, out);
}

// Round 9
// 140.310 us; speedup vs baseline: 1.4850x; 1.2681x over previous
//
#include <hip/hip_runtime.h>
#include <math.h>

#define NTOK 32768
#define KCB  1024
#define DIM  64
#define THETA 0.02f   // hi/lo-bf16 MFMA dist error bound ~1e-3; 20x margin

typedef __attribute__((ext_vector_type(8))) short short8;
typedef __attribute__((ext_vector_type(4))) float f32x4;
#define MFMA __builtin_amdgcn_mfma_f32_16x16x32_bf16

// ---- workspace layout (float word offsets) ----
#define WS_XR      0                       // [NTOK*64] rotated vectors f32
#define WS_ENORM   2097152                 // [1024] ||e_k||^2
#define WS_EH      2098176                 // [1024*64 bf16 = 32768 words] E hi
#define WS_EL      2130944                 // [32768 words] E lo
#define WS_COUNTS  2163712                 // [1024]
#define WS_CS      2164736                 // [1024]
#define WS_XRSUM   2165760                 // [64]
#define WS_ESUM    2165824                 // [64]
#define WS_SCAL    2165888                 // [16]: 0=sq_sum 1=xrnorm 2=c*emb^2
#define WS_FLAGCNT 2165904                 // [16] (int, slot 0)
#define WS_IDX     2165920                 // [NTOK] int
#define WS_FLAG    2198688                 // [NTOK] int flagged tokens
#define WS_SORT    2231456                 // [NTOK] int
#define WS_OFF     2264224                 // [1024] int
#define WS_CUR     2265248                 // [1024] int

// ---- output layout (float offsets) ----
#define O_Q    0
#define O_CB   2097152
#define O_CM   2097153
#define O_DV   2097154
#define O_PP   2097155
#define O_IDX  2097156
#define O_CS   2129924
#define O_EW   2130948
#define O_EMB  2196484

__device__ __forceinline__ void hilo(float v, unsigned &h, unsigned &l)
{
    unsigned b  = __float_as_uint(v);
    unsigned hb = (b + 0x7FFFu + ((b >> 16) & 1u)) & 0xFFFF0000u;
    float lof   = v - __uint_as_float(hb);
    unsigned lb = __float_as_uint(lof);
    l = (lb + 0x7FFFu + ((lb >> 16) & 1u)) >> 16;
    h = hb >> 16;
}

// ---------------------------------------------------------------------------
// 1) rotate via cross-lane FWHT with coalesced LDS-transpose staging;
//    blocks >= 512: enorm + E hi/lo bf16 prep.
__global__ __launch_bounds__(256) void k_rotate_enorm(const float* __restrict__ x,
    const float* __restrict__ E, float* __restrict__ xr, float* __restrict__ enorm,
    unsigned short* __restrict__ eh, unsigned short* __restrict__ el,
    float* __restrict__ xr_sum, float* __restrict__ scal)
{
    int tid = threadIdx.x;
    if (blockIdx.x >= 512) {   // E-prep blocks (4 x 256 codes)
        int k = ((int)blockIdx.x - 512) * 256 + tid;
        const float* ep = E + ((size_t)k << 6);
        unsigned* ehw = (unsigned*)eh + (k << 5);
        unsigned* elw = (unsigned*)el + (k << 5);
        float s = 0.f;
        #pragma unroll
        for (int q = 0; q < 32; ++q) {
            float v0 = ep[2*q], v1 = ep[2*q+1];
            s = fmaf(v0, v0, s); s = fmaf(v1, v1, s);
            unsigned h0, l0, h1, l1;
            hilo(v0, h0, l0);
            hilo(v1, h1, l1);
            ehw[q] = h0 | (h1 << 16);
            elw[q] = l0 | (l1 << 16);
        }
        enorm[k] = s;
        return;
    }
    __shared__ float xt[64 * 65];   // [c][s] tile, pad 65 -> conflict-free
    __shared__ float xs[4][64];
    __shared__ float wred[4];
    int p  = blockIdx.x >> 4;           // batch plane
    int s0 = ((int)blockIdx.x & 15) << 6;

    {   // coalesced stage: 64 c-rows x 64 s (256B contiguous per row)
        const float4* x4 = (const float4*)x;
        #pragma unroll
        for (int pass = 0; pass < 4; ++pass) {
            int q = (pass << 8) + tid;
            int c = q >> 4, col = (q & 15) << 2;
            float4 v = x4[(p << 14) + (c << 8) + (s0 >> 2) + (col >> 2)];
            float* dst = xt + c * 65 + col;
            dst[0] = v.x; dst[1] = v.y; dst[2] = v.z; dst[3] = v.w;
        }
    }
    __syncthreads();

    int lane = tid & 63, w = tid >> 6;
    float dsum = 0.f, nrm = 0.f;
    #pragma unroll
    for (int i = 0; i < 4; ++i) {
        int sl = (w << 4) + (i << 2);       // 4 local tokens
        const float* src = xt + lane * 65 + sl;
        float4 v = make_float4(src[0], src[1], src[2], src[3]);
        #pragma unroll
        for (int s = 1; s <= 32; s <<= 1) {
            float sgn = (lane & s) ? -1.f : 1.f;
            float ox = __shfl_xor(v.x, s);
            float oy = __shfl_xor(v.y, s);
            float oz = __shfl_xor(v.z, s);
            float ow = __shfl_xor(v.w, s);
            v.x = fmaf(sgn, v.x, ox);
            v.y = fmaf(sgn, v.y, oy);
            v.z = fmaf(sgn, v.z, oz);
            v.w = fmaf(sgn, v.w, ow);
        }
        int t0 = ((int)blockIdx.x << 6) + sl;
        float* dst = xr + ((size_t)t0 << 6) + lane;
        dst[0]   = v.x;
        dst[64]  = v.y;
        dst[128] = v.z;
        dst[192] = v.w;
        dsum += v.x + v.y + v.z + v.w;
        nrm  += v.x*v.x + v.y*v.y + v.z*v.z + v.w*v.w;
    }
    xs[w][lane] = dsum;
    #pragma unroll
    for (int m = 32; m >= 1; m >>= 1) nrm += __shfl_xor(nrm, m);
    if (lane == 0) wred[w] = nrm;
    __syncthreads();
    if (tid < 64) atomicAdd(&xr_sum[tid], xs[0][tid] + xs[1][tid] + xs[2][tid] + xs[3][tid]);
    if (tid == 0) atomicAdd(&scal[1], wred[0] + wred[1] + wred[2] + wred[3]);
}

// ---------------------------------------------------------------------------
// 2) MFMA argmin. Block = 32 tokens x 1024 codes; 1024 blocks -> 4 blocks/CU
//    (33.7KB LDS, VGPR<=128 via launch_bounds) = 4 waves/SIMD to hide the
//    MFMA dep chains. 4 waves = 2 token-sets x 2 code-halves; 8 chunks of
//    128 codes staged XOR-swizzled; cross-half top-2 merge in LDS at end.
__global__ __launch_bounds__(256, 4) void k_argmin(const float* __restrict__ xr,
    const unsigned short* __restrict__ eh, const unsigned short* __restrict__ el,
    const float* __restrict__ enorm, int* __restrict__ idxw,
    float* __restrict__ out_idx, float* __restrict__ counts,
    int* __restrict__ flagcnt, int* __restrict__ flaglist)
{
    __shared__ uint4 ehs[1024];    // 128 codes x 128B (swizzled)
    __shared__ uint4 els[1024];
    __shared__ float ens[128];
    __shared__ float m_b1[32], m_b2[32];
    __shared__ int   m_id[32];
    int tid = threadIdx.x;
    int lane = tid & 63, w = tid >> 6;
    int ts = w >> 1, kh = w & 1;       // token-set, code-half
    int tx = lane & 15, gq = lane >> 4;
    int tokbase = ((int)blockIdx.x << 5) + (ts << 4);

    // --- A fragments: token rows -> bf16 hi/lo in registers ---
    short8 ah0, al0, ah1, al1;
    {
        const float* xp = xr + ((size_t)(tokbase + tx) << 6) + (gq << 3);
        float4 xa = *(const float4*)(xp);
        float4 xb = *(const float4*)(xp + 4);
        float4 xc = *(const float4*)(xp + 32);
        float4 xd = *(const float4*)(xp + 36);
        float a0v[8] = {xa.x,xa.y,xa.z,xa.w,xb.x,xb.y,xb.z,xb.w};
        float a1v[8] = {xc.x,xc.y,xc.z,xc.w,xd.x,xd.y,xd.z,xd.w};
        #pragma unroll
        for (int j = 0; j < 8; ++j) {
            unsigned h, l;
            hilo(a0v[j], h, l);
            ah0[j] = (short)h; al0[j] = (short)l;
            hilo(a1v[j], h, l);
            ah1[j] = (short)h; al1[j] = (short)l;
        }
    }

    float b1[4], b2[4]; int idx[4];
    #pragma unroll
    for (int r = 0; r < 4; ++r) { b1[r] = 3.4e38f; b2[r] = 3.4e38f; idx[r] = 0; }

    int swz0 = gq ^ (tx & 7);
    int swz1 = (4 + gq) ^ (tx & 7);
    const f32x4 z4 = {0.f, 0.f, 0.f, 0.f};

    for (int ch = 0; ch < 8; ++ch) {
        int c0 = ch << 7;
        __syncthreads();
        {   // stage 128 codes of eh/el (+enorm), XOR-swizzled 16B units
            const uint4* ghs = (const uint4*)eh + ((size_t)c0 << 3);
            const uint4* gls = (const uint4*)el + ((size_t)c0 << 3);
            #pragma unroll
            for (int i = 0; i < 4; ++i) {
                int u = (i << 8) + tid;
                int rr = u >> 3, bb = u & 7;
                int bs = bb ^ (rr & 7);
                ehs[(rr << 3) + bs] = ghs[u];
                els[(rr << 3) + bs] = gls[u];
            }
            if (tid < 128) ens[tid] = enorm[c0 + tid];
        }
        __syncthreads();

        #pragma unroll
        for (int s = 0; s < 4; ++s) {
            int rbase = (kh << 6) + (s << 4) + tx;     // chunk-local code row
            short8 bh0 = ((const short8*)ehs)[(rbase << 3) + swz0];
            short8 bh1 = ((const short8*)ehs)[(rbase << 3) + swz1];
            short8 bl0 = ((const short8*)els)[(rbase << 3) + swz0];
            short8 bl1 = ((const short8*)els)[(rbase << 3) + swz1];

            f32x4 a0 = MFMA(ah0, bh0, z4, 0, 0, 0);
            a0 = MFMA(ah0, bl0, a0, 0, 0, 0);
            a0 = MFMA(al0, bh0, a0, 0, 0, 0);
            f32x4 a1 = MFMA(ah1, bh1, z4, 0, 0, 0);
            a1 = MFMA(ah1, bl1, a1, 0, 0, 0);
            a1 = MFMA(al1, bh1, a1, 0, 0, 0);

            float en = ens[rbase];
            int kk = c0 + rbase;
            #pragma unroll
            for (int r = 0; r < 4; ++r) {
                float sv = fmaf(-2.f, a0[r], fmaf(-2.f, a1[r], en));
                float mx = fmaxf(sv, b1[r]);
                b2[r] = fminf(b2[r], mx);
                bool t = sv < b1[r];
                idx[r] = t ? kk : idx[r];
                b1[r] = fminf(b1[r], sv);
            }
        }
    }

    // reduce across 16 code-columns (tx bits 0-3)
    float v1f[4], v2f[4]; int idf[4];
    #pragma unroll
    for (int r = 0; r < 4; ++r) {
        float v1 = b1[r], v2 = b2[r]; int id = idx[r];
        #pragma unroll
        for (int m = 1; m <= 8; m <<= 1) {
            float o1 = __shfl_xor(v1, m);
            float o2 = __shfl_xor(v2, m);
            int   oi = __shfl_xor(id, m);
            float nb2 = fminf(fminf(v2, o2), fmaxf(v1, o1));
            bool t = (o1 < v1) || (o1 == v1 && oi < id);
            v1 = t ? o1 : v1;
            id = t ? oi : id;
            v2 = nb2;
        }
        v1f[r] = v1; v2f[r] = v2; idf[r] = id;
    }

    // cross code-half merge via LDS
    int tl = (ts << 4) + (gq << 2);
    if (kh == 1 && tx == 0) {
        #pragma unroll
        for (int r = 0; r < 4; ++r) {
            m_b1[tl + r] = v1f[r];
            m_b2[tl + r] = v2f[r];
            m_id[tl + r] = idf[r];
        }
    }
    __syncthreads();
    if (kh == 0 && tx == 0) {
        #pragma unroll
        for (int r = 0; r < 4; ++r) {
            float o1 = m_b1[tl + r], o2 = m_b2[tl + r];
            int   oi = m_id[tl + r];
            float v1 = v1f[r]; int id = idf[r];
            float b2m = fminf(fminf(v2f[r], o2), fmaxf(v1, o1));
            bool t = (o1 < v1) || (o1 == v1 && oi < id);
            float v1m = t ? o1 : v1;
            int   idm = t ? oi : id;
            int tok = tokbase + (gq << 2) + r;
            idxw[tok] = idm;
            out_idx[tok] = (float)idm;
            atomicAdd(&counts[idm], 1.f);
            if (b2m - v1m < THETA) {
                int pz = atomicAdd(flagcnt, 1);
                flaglist[pz] = tok;
            }
        }
    }
}

// ---------------------------------------------------------------------------
// 3) exact f32 re-scan for flagged (near-tie) tokens; corrects idx/counts.
#define NFWAVE 512
__global__ __launch_bounds__(256) void k_fixup(const float* __restrict__ xr,
    const float* __restrict__ E, const float* __restrict__ enorm,
    const int* __restrict__ flagcnt, const int* __restrict__ flaglist,
    int* __restrict__ idxw, float* __restrict__ out_idx, float* __restrict__ counts)
{
    int lane = threadIdx.x & 63;
    int wid = ((int)blockIdx.x * 256 + threadIdx.x) >> 6;
    int cnt = flagcnt[0];
    for (int i = wid; i < cnt; i += NFWAVE) {
        int tok = flaglist[i];
        const float4* xp = (const float4*)(xr + ((size_t)tok << 6));
        float4 xa[16];
        #pragma unroll
        for (int q = 0; q < 16; ++q) xa[q] = xp[q];
        float best = 3.4e38f; int bidx = 0;
        for (int c = 0; c < 16; ++c) {
            int k = (c << 6) + lane;
            const float4* epp = (const float4*)(E + ((size_t)k << 6));
            float d = 0.f;
            #pragma unroll
            for (int q = 0; q < 16; ++q) {
                float4 e = epp[q];
                d = fmaf(xa[q].x, e.x, d);
                d = fmaf(xa[q].y, e.y, d);
                d = fmaf(xa[q].z, e.z, d);
                d = fmaf(xa[q].w, e.w, d);
            }
            float sv = fmaf(-2.f, d, enorm[k]);
            if (sv < best) { best = sv; bidx = k; }
        }
        #pragma unroll
        for (int m = 1; m <= 32; m <<= 1) {
            float ov = __shfl_xor(best, m);
            int   oi = __shfl_xor(bidx, m);
            if (ov < best || (ov == best && oi < bidx)) { best = ov; bidx = oi; }
        }
        if (lane == 0) {
            int old = idxw[tok];
            if (old != bidx) {
                atomicAdd(&counts[old], -1.f);
                atomicAdd(&counts[bidx], 1.f);
                idxw[tok] = bidx;
                out_idx[tok] = (float)bidx;
            }
        }
    }
}

// ---------------------------------------------------------------------------
// 4) EMA cluster size + smoothing + exclusive scan (wave-shuffle)
__global__ __launch_bounds__(1024) void k_ema_scan(const float* __restrict__ ecs,
    const float* __restrict__ counts, float* __restrict__ out_cs,
    float* __restrict__ csw, int* __restrict__ off, int* __restrict__ cur)
{
    __shared__ float wsum[16];
    __shared__ int   wcnt[16];
    __shared__ int   woff[16];
    __shared__ float nss;
    int k = threadIdx.x;
    int lane = k & 63, w = k >> 6;
    float c = counts[k];
    float cs = ecs[k] * 0.99f + 0.01f * c;
    int ci = (int)c;
    int sc = ci;
    #pragma unroll
    for (int o = 1; o < 64; o <<= 1) {
        int t = __shfl_up(sc, o);
        if (lane >= o) sc += t;
    }
    float v = cs;
    #pragma unroll
    for (int m = 32; m >= 1; m >>= 1) v += __shfl_xor(v, m);
    if (lane == 63) wcnt[w] = sc;
    if (lane == 0)  wsum[w] = v;
    __syncthreads();
    if (k < 16) {
        int t = wcnt[k];
        int e = t;
        #pragma unroll
        for (int o = 1; o < 16; o <<= 1) {
            int u = __shfl_up(e, o);
            if (k >= o) e += u;
        }
        woff[k] = e - t;
        if (k == 15) {
            float s = 0.f;
            for (int i = 0; i < 16; ++i) s += wsum[i];
            nss = s;
        }
    }
    __syncthreads();
    int offk = woff[w] + sc - ci;
    off[k] = offk;
    cur[k] = offk;
    float nn = nss;
    float csf = (cs + 1e-5f) / (nn + 1024.f * 1e-5f) * nn;
    out_cs[k] = csf;
    csw[k] = csf;
}

// ---------------------------------------------------------------------------
// 5) fused quant output + sq-error + counting-sort scatter
__global__ __launch_bounds__(256) void k_quantscatter(const float* __restrict__ x,
    const float* __restrict__ E, const int* __restrict__ idxw,
    int* __restrict__ cur, int* __restrict__ sorted,
    float* __restrict__ outq, float* __restrict__ scal)
{
    __shared__ int lidx[256];
    __shared__ float wr[4];
    int tid = threadIdx.x;
    int n = blockIdx.x * 256 + tid;
    int k = idxw[n];
    lidx[tid] = k;
    int pos = atomicAdd(&cur[k], 1);
    sorted[pos] = n;
    __syncthreads();

    int f40 = blockIdx.x * 4096;
    float sq = 0.f;
    #pragma unroll 4
    for (int it = 0; it < 16; ++it) {
        int q = (it << 8) + tid;
        int kk = lidx[q >> 4];
        int d4 = q & 15;
        float4 xv = ((const float4*)x)[f40 + q];
        float4 ev = ((const float4*)E)[(kk << 4) + d4];
        float dx = ev.x - xv.x, dy = ev.y - xv.y, dz = ev.z - xv.z, dw_ = ev.w - xv.w;
        ((float4*)outq)[f40 + q] = make_float4(xv.x + dx, xv.y + dy, xv.z + dz, xv.w + dw_);
        sq += dx*dx + dy*dy + dz*dz + dw_*dw_;
    }
    #pragma unroll
    for (int m = 32; m >= 1; m >>= 1) sq += __shfl_xor(sq, m);
    if ((tid & 63) == 0) wr[tid >> 6] = sq;
    __syncthreads();
    if (tid == 0) atomicAdd(&scal[0], wr[0] + wr[1] + wr[2] + wr[3]);
}

// ---------------------------------------------------------------------------
// 6) per-code segmented reduction -> new_ema_w, new_embedding, diversity
__global__ __launch_bounds__(256) void k_dwemb(const float* __restrict__ xr,
    const int* __restrict__ sorted, const int* __restrict__ off,
    const float* __restrict__ counts, const float* __restrict__ csw,
    const float* __restrict__ emaw, float* __restrict__ out_ew,
    float* __restrict__ out_emb, float* __restrict__ e_sum,
    float* __restrict__ scal)
{
    __shared__ float part[3][64];
    int k = blockIdx.x;
    int tid = threadIdx.x;
    int w = tid >> 6, d = tid & 63;
    int a = off[k];
    int cnt = (int)counts[k];
    int end = a + cnt;

    float sum = 0.f;
    for (int t = a + w; t < end; t += 4) {
        int tok = sorted[t];
        sum += xr[((size_t)tok << 6) + d];
    }
    if (w) part[w - 1][d] = sum;
    __syncthreads();
    if (w == 0) {
        float dw = sum + part[0][d] + part[1][d] + part[2][d];
        int i = (k << 6) + d;
        float nw = emaw[i] * 0.99f + 0.01f * dw;
        out_ew[i] = nw;
        float emb = nw / csw[k];
        out_emb[i] = emb;
        if (cnt > 0) {
            float c = (float)cnt;
            atomicAdd(&e_sum[d], c * emb);
            float t2 = c * emb * emb;
            #pragma unroll
            for (int m = 32; m >= 1; m >>= 1) t2 += __shfl_xor(t2, m);
            if (d == 0) atomicAdd(&scal[2], t2);
        }
    }
}

// ---------------------------------------------------------------------------
// 7) finalize scalars
__global__ __launch_bounds__(1024) void k_final(const float* __restrict__ counts,
    const float* __restrict__ scal, const float* __restrict__ xr_sum,
    const float* __restrict__ e_sum, float* __restrict__ out)
{
    int tid = threadIdx.x;
    float a = counts[tid] * (1.f / 32768.f);
    float t = a * logf(a + 1e-10f);
    float dc = (tid < 64) ? e_sum[tid] * xr_sum[tid] : 0.f;
    #pragma unroll
    for (int m = 32; m >= 1; m >>= 1) { t += __shfl_xor(t, m); dc += __shfl_xor(dc, m); }
    __shared__ float wt[16], wd[16];
    if ((tid & 63) == 0) { wt[tid >> 6] = t; wd[tid >> 6] = dc; }
    __syncthreads();
    if (tid == 0) {
        float S = 0.f, Dt = 0.f;
        for (int i = 0; i < 16; ++i) { S += wt[i]; Dt += wd[i]; }
        float cb = scal[0] * (1.f / 2097152.f);
        out[O_CB] = cb;
        out[O_CM] = 0.25f * cb;
        float inv = 1.f / 32768.f;
        out[O_DV] = scal[2] * inv + scal[1] * inv - 2.f * (Dt * inv * inv);
        out[O_PP] = expf(-S);
    }
}

// ---------------------------------------------------------------------------
extern "C" void kernel_launch(void* const* d_in, const int* in_sizes, int n_in,
                              void* d_out, int out_size, void* d_ws, size_t ws_size,
                              hipStream_t stream)
{
    const float* x    = (const float*)d_in[0];
    const float* E    = (const float*)d_in[1];
    const float* emaw = (const float*)d_in[3];
    const float* ecs  = (const float*)d_in[4];
    float* out = (float*)d_out;
    float* ws  = (float*)d_ws;

    // zero: counts, cs, xrsum, esum, scal, flagcnt (contiguous)
    hipMemsetAsync((void*)(ws + WS_COUNTS), 0,
                   (size_t)(WS_IDX - WS_COUNTS) * sizeof(float), stream);

    hipLaunchKernelGGL(k_rotate_enorm, dim3(516), dim3(256), 0, stream,
                       x, E, ws + WS_XR, ws + WS_ENORM,
                       (unsigned short*)(ws + WS_EH), (unsigned short*)(ws + WS_EL),
                       ws + WS_XRSUM, ws + WS_SCAL);
    hipLaunchKernelGGL(k_argmin, dim3(1024), dim3(256), 0, stream,
                       ws + WS_XR, (const unsigned short*)(ws + WS_EH),
                       (const unsigned short*)(ws + WS_EL), ws + WS_ENORM,
                       (int*)(ws + WS_IDX), out + O_IDX, ws + WS_COUNTS,
                       (int*)(ws + WS_FLAGCNT), (int*)(ws + WS_FLAG));
    hipLaunchKernelGGL(k_fixup, dim3(128), dim3(256), 0, stream,
                       ws + WS_XR, E, ws + WS_ENORM,
                       (const int*)(ws + WS_FLAGCNT), (const int*)(ws + WS_FLAG),
                       (int*)(ws + WS_IDX), out + O_IDX, ws + WS_COUNTS);
    hipLaunchKernelGGL(k_ema_scan, dim3(1), dim3(1024), 0, stream,
                       ecs, ws + WS_COUNTS, out + O_CS, ws + WS_CS,
                       (int*)(ws + WS_OFF), (int*)(ws + WS_CUR));
    hipLaunchKernelGGL(k_quantscatter, dim3(128), dim3(256), 0, stream,
                       x, E, (const int*)(ws + WS_IDX), (int*)(ws + WS_CUR),
                       (int*)(ws + WS_SORT), out + O_Q, ws + WS_SCAL);
    hipLaunchKernelGGL(k_dwemb, dim3(1024), dim3(256), 0, stream,
                       ws + WS_XR, (const int*)(ws + WS_SORT),
                       (const int*)(ws + WS_OFF), ws + WS_COUNTS, ws + WS_CS,
                       emaw, out + O_EW, out + O_EMB, ws + WS_ESUM, ws + WS_SCAL);
    hipLaunchKernelGGL(k_final, dim3(1), dim3(1024), 0, stream,
                       ws + WS_COUNTS, ws + WS_SCAL, ws + WS_XRSUM,
                       ws + WS_ESUM, out);
}